// Round 17
// baseline (498.625 us; speedup 1.0000x reference)
//
#include <hip/hip_runtime.h>

#define B_  2
#define S_  1024
#define D_  4096
#define H_  32
#define HD_ 128
#define T_  (B_*S_)   // 2048 tokens

typedef short s16x8 __attribute__((ext_vector_type(8)));   // 8 bf16 (4 VGPRs)
typedef float f32x4 __attribute__((ext_vector_type(4)));
typedef unsigned short u16;

__device__ __forceinline__ u16 f2bf(float f) {
  unsigned int u = __float_as_uint(f);
  u += 0x7fffu + ((u >> 16) & 1u);     // round-to-nearest-even
  return (u16)(u >> 16);
}
__device__ __forceinline__ float bf2f(u16 h) {
  return __uint_as_float(((unsigned int)h) << 16);
}
__device__ __forceinline__ void gload_lds16(const void* g, void* l) {
  __builtin_amdgcn_global_load_lds(
      (const __attribute__((address_space(1))) unsigned int*)g,
      (__attribute__((address_space(3))) unsigned int*)l, 16, 0, 0);
}
#define MFMA16(a, b, c) __builtin_amdgcn_mfma_f32_16x16x32_bf16((a), (b), (c), 0, 0, 0)

// ------- merged f32 -> bf16 convert: x | wq | wk | wv (wo moved to attn) ----
__global__ __launch_bounds__(256) void cvt_all(const float* __restrict__ x,
                                               const float* __restrict__ wq,
                                               const float* __restrict__ wk,
                                               const float* __restrict__ wv,
                                               u16* __restrict__ xb,
                                               u16* __restrict__ wb) {
  const int n8x = T_ * D_ / 8;                 // 2^20
  const int n8w = D_ * D_ / 8;                 // 2^21
  const int total = n8x + 3 * n8w;
  for (int i = blockIdx.x * 256 + threadIdx.x; i < total; i += gridDim.x * 256) {
    const float* src;
    u16* dst;
    int off;
    if (i < n8x) { src = x; dst = xb; off = i; }
    else {
      const int j = i - n8x;
      const int seg = j >> 21;                 // 0..2
      off = j & (n8w - 1);
      src = (seg == 0) ? wq : (seg == 1) ? wk : wv;
      dst = wb + ((size_t)seg << 24);          // seg * D_*D_
    }
    const float4* p = (const float4*)src + (size_t)off * 2;
    float4 a = p[0], b = p[1];
    u16 us[8] = {f2bf(a.x), f2bf(a.y), f2bf(a.z), f2bf(a.w),
                 f2bf(b.x), f2bf(b.y), f2bf(b.z), f2bf(b.w)};
    *(uint4*)(dst + (size_t)off * 8) = *(uint4*)us;
  }
}

// ---- stage one 128x64 bf16 tile, NW waves. Linear LDS dest [128][64],
// pre-swizzled source: stored 16B-slot s at row r holds logical col16 s^(r&7)
template <int NW>
__device__ __forceinline__ void stage_tile(const u16* __restrict__ g, int ldk,
                                           int row0, int k0, u16* lds,
                                           int wid, int lane) {
  const int rsub = lane >> 3;           // 0..7 row within chunk
  const int c16  = (lane & 7) ^ rsub;   // pre-swizzled source col16
#pragma unroll
  for (int l = 0; l < 16 / NW; ++l) {
    const int c = wid * (16 / NW) + l;  // chunk 0..15 (8 rows each)
    gload_lds16(g + (size_t)(row0 + c * 8 + rsub) * ldk + k0 + c16 * 8,
                lds + c * 512);
  }
}

// ========== 128x256 2-phase counted-vmcnt GEMM (R7/R9/R16-validated) =======
// EPI: 0 = f32 out (out-proj). 1 = Q (RoPE + exp2-domain scale). 2 = K
// (RoPE). 3 = V (transposed (b,h,d,s) write). Grid 256 blocks = 1/CU; W is
// 32MB L3-resident per dispatch (the R8-failure mechanism test: 3 sequential
// L3-hot dispatches vs one 96MB-streaming fused dispatch).
template <int EPI>
__global__ __launch_bounds__(512, 2) void gemm2p(const u16* __restrict__ A,
                                                 const u16* __restrict__ W,
                                                 u16* __restrict__ Ob16,
                                                 float* __restrict__ Of,
                                                 const float* __restrict__ cosb,
                                                 const float* __restrict__ sinb,
                                                 int MB, int NB, int K) {
  __shared__ __align__(16) u16 LA[2][128 * 64];     // 32KB
  __shared__ __align__(16) u16 LB[2][2][128 * 64];  // 64KB
  const int nwg = MB * NB;
  const int cpx = nwg >> 3;
  const int bid = blockIdx.x;
  const int swz = (bid & 7) * cpx + (bid >> 3);
  const int bm = swz / NB, bn = swz % NB;           // N-fastest
  const int m0 = bm * 128, n0 = bn * 256;
  const int tid = threadIdx.x, wid = tid >> 6, lane = tid & 63;
  const int wr = wid >> 2, wc = wid & 3;            // 2x4 wave grid
  const int fr = lane & 15, fq = lane >> 4;
  const int nkt = K >> 6;
  f32x4 acc[4][4] = {};

  auto STAGE = [&](int gidx) {   // gidx = tile*3 + part, parts {B0,B1,A}
    if (gidx >= 3 * nkt) return;
    const int t = gidx / 3, part = gidx - 3 * t, slot = t & 1, k0 = t * 64;
    if (part < 2)
      stage_tile<8>(W, K, n0 + part * 128, k0, &LB[slot][part][0], wid, lane);
    else
      stage_tile<8>(A, K, m0, k0, &LA[slot][0], wid, lane);
  };

  for (int g = 0; g < 5; ++g) STAGE(g);             // t0 full + t1 {B0,B1}
  asm volatile("s_waitcnt vmcnt(4)" ::: "memory");  // t0 landed
  __builtin_amdgcn_s_barrier();

  for (int t = 0; t < nkt; ++t) {
    const int slot = t & 1;
    s16x8 af[2][2], bfr[4][2];
#pragma unroll
    for (int i = 0; i < 2; ++i)
#pragma unroll
      for (int kk = 0; kk < 2; ++kk) {
        const int r = wr * 64 + i * 16 + fr;
        const int s16 = (kk * 4 + fq) ^ (r & 7);
        af[i][kk] = *(const s16x8*)&LA[slot][r * 64 + s16 * 8];
      }
#pragma unroll
    for (int ni = 0; ni < 4; ++ni)
#pragma unroll
      for (int kk = 0; kk < 2; ++kk) {
        const int rr = (wc & 1) * 64 + ni * 16 + fr;
        const int s16 = (kk * 4 + fq) ^ (rr & 7);
        bfr[ni][kk] = *(const s16x8*)&LB[slot][wc >> 1][rr * 64 + s16 * 8];
      }
    STAGE(3 * t + 5);                    // t+1: A (other slot, WAR-safe)
    __builtin_amdgcn_s_barrier();
    __builtin_amdgcn_s_setprio(1);
#pragma unroll
    for (int kk = 0; kk < 2; ++kk)       // kk outer: dep distance 8
#pragma unroll
      for (int i = 0; i < 2; ++i)
#pragma unroll
        for (int ni = 0; ni < 4; ++ni)
          acc[i][ni] = MFMA16(af[i][kk], bfr[ni][kk], acc[i][ni]);
    __builtin_amdgcn_s_setprio(0);
    __builtin_amdgcn_s_barrier();
#pragma unroll
    for (int i = 0; i < 2; ++i)
#pragma unroll
      for (int kk = 0; kk < 2; ++kk) {
        const int r = wr * 64 + (2 + i) * 16 + fr;
        const int s16 = (kk * 4 + fq) ^ (r & 7);
        af[i][kk] = *(const s16x8*)&LA[slot][r * 64 + s16 * 8];
      }
    STAGE(3 * t + 6);                    // t+2: B0 (post-ph0-barrier WAR-safe)
    STAGE(3 * t + 7);                    // t+2: B1
    if (t < nkt - 2) asm volatile("s_waitcnt vmcnt(4)" ::: "memory"); // t+1 landed
    else             asm volatile("s_waitcnt vmcnt(0)" ::: "memory");
    __builtin_amdgcn_s_barrier();
    __builtin_amdgcn_s_setprio(1);
#pragma unroll
    for (int kk = 0; kk < 2; ++kk)
#pragma unroll
      for (int i = 0; i < 2; ++i)
#pragma unroll
        for (int ni = 0; ni < 4; ++ni)
          acc[2 + i][ni] = MFMA16(af[i][kk], bfr[ni][kk], acc[2 + i][ni]);
    __builtin_amdgcn_s_setprio(0);
    __builtin_amdgcn_s_barrier();
  }

  // epilogue: D(i,j): col = lane&15, row = (lane>>4)*4 + reg  [m89-verified]
  if (EPI == 0) {                        // ---- f32 out (out-proj) ----
    const int Nn = NB * 256;
#pragma unroll
    for (int mi = 0; mi < 4; ++mi)
#pragma unroll
      for (int ni = 0; ni < 4; ++ni) {
        const int col = n0 + wc * 64 + ni * 16 + fr;
#pragma unroll
        for (int r = 0; r < 4; ++r) {
          const int row = m0 + wr * 64 + mi * 16 + fq * 4 + r;
          Of[(size_t)row * Nn + col] = acc[mi][ni][r];
        }
      }
  } else if (EPI == 1 || EPI == 2) {     // ---- Q/K: fused RoPE ----
    const float qsc = (EPI == 1) ? 0.12751741f : 1.0f;  // 1/sqrt(128)*log2e
    const float sgn = (fr & 1) ? 1.f : -1.f;   // even lane: t0*c - t1*s
#pragma unroll
    for (int mi = 0; mi < 4; ++mi)
#pragma unroll
      for (int ni = 0; ni < 4; ++ni) {
        const int col = n0 + wc * 64 + ni * 16 + fr;
        const int i0 = (col & (HD_ - 1)) >> 1;
#pragma unroll
        for (int r = 0; r < 4; ++r) {
          const int row = m0 + wr * 64 + mi * 16 + fq * 4 + r;
          const int s = row & (S_ - 1);
          const float v  = acc[mi][ni][r];
          const float vo = __shfl_xor(v, 1);
          const float c  = cosb[s * (HD_ / 2) + i0];
          const float sn = sinb[s * (HD_ / 2) + i0];
          Ob16[(size_t)row * 4096 + col] = f2bf((v * c + sgn * vo * sn) * qsc);
        }
      }
  } else {                               // ---- V: write transposed (b,h,d,s)
#pragma unroll
    for (int mi = 0; mi < 4; ++mi)
#pragma unroll
      for (int ni = 0; ni < 4; ++ni) {
        const int col = n0 + wc * 64 + ni * 16 + fr;
        const int h = col >> 7, d = col & (HD_ - 1);
        const int row0 = m0 + wr * 64 + mi * 16 + fq * 4;
        const int bb = row0 >> 10, s0 = row0 & (S_ - 1);
        ushort4 w;
        w.x = f2bf(acc[mi][ni][0]); w.y = f2bf(acc[mi][ni][1]);
        w.z = f2bf(acc[mi][ni][2]); w.w = f2bf(acc[mi][ni][3]);
        *(ushort4*)&Ob16[((size_t)(bb * H_ + h) * HD_ + d) * S_ + s0] = w;
      }
  }
}

// ---------------- Flash attention: Q-tile 128, 8 waves x 16 q-rows ---------
// Static-max softmax (R12-proven); wo f32->bf16 fused under idle HBM.
__global__ __launch_bounds__(512) void flash_attn(const u16* __restrict__ qb,
                                                  const u16* __restrict__ kb,
                                                  const u16* __restrict__ vtb,
                                                  u16* __restrict__ ab,
                                                  const float* __restrict__ wo,
                                                  u16* __restrict__ wob) {
  __shared__ __align__(16) u16 Ks[128 * 64];   // row = (kcol>>6)*64 + key
  __shared__ __align__(16) u16 Vs[128 * 64];   // row = d, cols = 64 keys
  __shared__ __align__(16) u16 Ps[8][16][72];
  const int qt = blockIdx.x, h = blockIdx.y, b = blockIdx.z;
  const int tid = threadIdx.x, wid = tid >> 6, lane = tid & 63;
  const int fr = lane & 15, fq = lane >> 4;
  const int rsub = lane >> 3;           // staging row-within-chunk
  const int c16  = (lane & 7) ^ rsub;   // pre-swizzled source col16

  {  // fused wo convert (consumer is a later dispatch; no sync needed)
    const int bidf = (b * H_ + h) * (S_ / 128) + qt;   // 0..511
    const int n8w = D_ * D_ / 8;
    for (int i = bidf * 512 + tid; i < n8w; i += 512 * 512) {
      const float4* p = (const float4*)wo + (size_t)i * 2;
      float4 a = p[0], bb4 = p[1];
      u16 us[8] = {f2bf(a.x), f2bf(a.y), f2bf(a.z), f2bf(a.w),
                   f2bf(bb4.x), f2bf(bb4.y), f2bf(bb4.z), f2bf(bb4.w)};
      *(uint4*)(wob + (size_t)i * 8) = *(uint4*)us;
    }
  }

  const int q0 = qt * 128 + wid * 16;
  s16x8 qf[4];
  {
    size_t base = (size_t)(b * S_ + q0 + fr) * D_ + h * HD_;
#pragma unroll
    for (int kk = 0; kk < 4; ++kk) qf[kk] = *(const s16x8*)&qb[base + kk * 32 + fq * 8];
  }
  f32x4 oacc[8] = {};
  float l_i[4] = {0.f, 0.f, 0.f, 0.f};     // lane-partial (16 keys/lane-group)
  const float M2 = 23.083120654f;          // static offset; cancels in normalize
  const u16* vsrc = vtb + (size_t)(b * H_ + h) * HD_ * S_;

  for (int k0 = 0; k0 < S_; k0 += 64) {
    __syncthreads();                     // prior-iter LDS reads complete
    {  // K: chunk c holds rows r=c*8+rsub, r=(kcol>>6)*64+key
      const u16* ksrc = kb + (size_t)(b * S_ + k0) * D_ + h * HD_;
#pragma unroll
      for (int l = 0; l < 2; ++l) {
        const int c = wid * 2 + l;
        const int key = (c & 7) * 8 + rsub, half = c >> 3;
        gload_lds16(ksrc + (size_t)key * D_ + half * 64 + c16 * 8, Ks + c * 512);
      }
      stage_tile<8>(vsrc, S_, 0, k0, Vs, wid, lane);
    }
    __syncthreads();                     // drains vmcnt: tiles resident
    f32x4 sacc[4] = {};
    __builtin_amdgcn_s_setprio(1);
#pragma unroll
    for (int kk = 0; kk < 4; ++kk)
#pragma unroll
      for (int nb = 0; nb < 4; ++nb)
        sacc[nb] = MFMA16(qf[kk],
            *(const s16x8*)&Ks[((kk >> 1) * 64 + nb * 16 + fr) * 64 +
                               ((((kk & 1) * 4 + fq) ^ (fr & 7)) * 8)],
            sacc[nb]);
    __builtin_amdgcn_s_setprio(0);
    // static-max softmax: 16 exp2 + 4 adds + LDS writes, no cross-lane ops
#pragma unroll
    for (int r = 0; r < 4; ++r) {
      const float p0 = __builtin_amdgcn_exp2f(sacc[0][r] - M2);
      const float p1 = __builtin_amdgcn_exp2f(sacc[1][r] - M2);
      const float p2 = __builtin_amdgcn_exp2f(sacc[2][r] - M2);
      const float p3 = __builtin_amdgcn_exp2f(sacc[3][r] - M2);
      l_i[r] += (p0 + p1) + (p2 + p3);
      Ps[wid][fq * 4 + r][0 * 16 + fr] = f2bf(p0);
      Ps[wid][fq * 4 + r][1 * 16 + fr] = f2bf(p1);
      Ps[wid][fq * 4 + r][2 * 16 + fr] = f2bf(p2);
      Ps[wid][fq * 4 + r][3 * 16 + fr] = f2bf(p3);
    }
    s16x8 pf0 = *(const s16x8*)&Ps[wid][fr][fq * 8];
    s16x8 pf1 = *(const s16x8*)&Ps[wid][fr][32 + fq * 8];
    __builtin_amdgcn_s_setprio(1);
#pragma unroll
    for (int db = 0; db < 8; ++db)
      oacc[db] = MFMA16(pf0,
          *(const s16x8*)&Vs[(db * 16 + fr) * 64 + ((fq ^ (fr & 7)) * 8)], oacc[db]);
#pragma unroll
    for (int db = 0; db < 8; ++db)
      oacc[db] = MFMA16(pf1,
          *(const s16x8*)&Vs[(db * 16 + fr) * 64 + (((4 + fq) ^ (fr & 7)) * 8)], oacc[db]);
    __builtin_amdgcn_s_setprio(0);
  }
  // epilogue: reduce lane-partial l across the 16 fr lanes, normalize, store
#pragma unroll
  for (int r = 0; r < 4; ++r) {
    float sum = l_i[r];
#pragma unroll
    for (int o = 1; o < 16; o <<= 1) sum += __shfl_xor(sum, o);
    const float inv = 1.0f / sum;
    size_t rowbase = (size_t)(b * S_ + q0 + fq * 4 + r) * D_ + h * HD_;
#pragma unroll
    for (int db = 0; db < 8; ++db)
      ab[rowbase + db * 16 + fr] = f2bf(oacc[db][r] * inv);
  }
}

// ---------------------------------------------------------------------------
extern "C" void kernel_launch(void* const* d_in, const int* in_sizes, int n_in,
                              void* d_out, int out_size, void* d_ws, size_t ws_size,
                              hipStream_t stream) {
  const float* x    = (const float*)d_in[0];
  const float* wq   = (const float*)d_in[1];
  const float* wk   = (const float*)d_in[2];
  const float* wv   = (const float*)d_in[3];
  const float* wo   = (const float*)d_in[4];
  const float* fcos = (const float*)d_in[7];
  const float* fsin = (const float*)d_in[8];
  float* out = (float*)d_out;

  u16* xb  = (u16*)d_ws;                      // T*D
  u16* wqb = xb + (size_t)T_ * D_;            // D*D each; wq|wk|wv CONTIGUOUS
  u16* wkb = wqb + (size_t)D_ * D_;
  u16* wvb = wkb + (size_t)D_ * D_;
  u16* wob = wvb + (size_t)D_ * D_;
  u16* qb  = wob + (size_t)D_ * D_;           // T*D each
  u16* kb  = qb + (size_t)T_ * D_;
  u16* vtb = kb + (size_t)T_ * D_;
  u16* ab  = vtb + (size_t)T_ * D_;

  // convert x + wq/wk/wv (wo converted inside flash_attn under idle HBM)
  cvt_all<<<2048, 256, 0, stream>>>(x, wq, wk, wv, xb, wqb);

  // QKV as 3 sequential L3-resident 2-phase dispatches (R8 mechanism test):
  // each W = 32MB (L3-hot), 256 blocks = 1/CU exact, validated schedule.
  gemm2p<1><<<256, 512, 0, stream>>>(xb, wqb, qb, nullptr, fcos, fsin, 16, 16, D_);
  gemm2p<2><<<256, 512, 0, stream>>>(xb, wkb, kb, nullptr, fcos, fsin, 16, 16, D_);
  gemm2p<3><<<256, 512, 0, stream>>>(xb, wvb, vtb, nullptr, nullptr, nullptr, 16, 16, D_);

  flash_attn<<<dim3(S_ / 128, H_, B_), 512, 0, stream>>>(qb, kb, vtb, ab, wo, wob);

  // output projection: 2-phase counted-vmcnt, 16x16 = 256 blocks (1/CU exact)
  gemm2p<0><<<256, 512, 0, stream>>>(ab, wob, nullptr, out, nullptr, nullptr, 16, 16, D_);
}

// Round 18
// 422.522 us; speedup vs baseline: 1.1801x; 1.1801x over previous
//
#include <hip/hip_runtime.h>

#define B_  2
#define S_  1024
#define D_  4096
#define H_  32
#define HD_ 128
#define T_  (B_*S_)   // 2048 tokens

typedef short s16x8 __attribute__((ext_vector_type(8)));   // 8 bf16 (4 VGPRs)
typedef float f32x4 __attribute__((ext_vector_type(4)));
typedef unsigned short u16;

__device__ __forceinline__ u16 f2bf(float f) {
  unsigned int u = __float_as_uint(f);
  u += 0x7fffu + ((u >> 16) & 1u);     // round-to-nearest-even
  return (u16)(u >> 16);
}
__device__ __forceinline__ float bf2f(u16 h) {
  return __uint_as_float(((unsigned int)h) << 16);
}
__device__ __forceinline__ void gload_lds16(const void* g, void* l) {
  __builtin_amdgcn_global_load_lds(
      (const __attribute__((address_space(1))) unsigned int*)g,
      (__attribute__((address_space(3))) unsigned int*)l, 16, 0, 0);
}
#define MFMA16(a, b, c) __builtin_amdgcn_mfma_f32_16x16x32_bf16((a), (b), (c), 0, 0, 0)

// ------- merged f32 -> bf16 convert: x | wq | wk | wv (wo moved to attn) ----
__global__ __launch_bounds__(256) void cvt_all(const float* __restrict__ x,
                                               const float* __restrict__ wq,
                                               const float* __restrict__ wk,
                                               const float* __restrict__ wv,
                                               u16* __restrict__ xb,
                                               u16* __restrict__ wb) {
  const int n8x = T_ * D_ / 8;                 // 2^20
  const int n8w = D_ * D_ / 8;                 // 2^21
  const int total = n8x + 3 * n8w;
  for (int i = blockIdx.x * 256 + threadIdx.x; i < total; i += gridDim.x * 256) {
    const float* src;
    u16* dst;
    int off;
    if (i < n8x) { src = x; dst = xb; off = i; }
    else {
      const int j = i - n8x;
      const int seg = j >> 21;                 // 0..2
      off = j & (n8w - 1);
      src = (seg == 0) ? wq : (seg == 1) ? wk : wv;
      dst = wb + ((size_t)seg << 24);          // seg * D_*D_
    }
    const float4* p = (const float4*)src + (size_t)off * 2;
    float4 a = p[0], b = p[1];
    u16 us[8] = {f2bf(a.x), f2bf(a.y), f2bf(a.z), f2bf(a.w),
                 f2bf(b.x), f2bf(b.y), f2bf(b.z), f2bf(b.w)};
    *(uint4*)(dst + (size_t)off * 8) = *(uint4*)us;
  }
}

// ---- stage one 128x64 bf16 tile, NW waves. Linear LDS dest [128][64],
// pre-swizzled source: stored 16B-slot s at row r holds logical col16 s^(r&7)
template <int NW>
__device__ __forceinline__ void stage_tile(const u16* __restrict__ g, int ldk,
                                           int row0, int k0, u16* lds,
                                           int wid, int lane) {
  const int rsub = lane >> 3;           // 0..7 row within chunk
  const int c16  = (lane & 7) ^ rsub;   // pre-swizzled source col16
#pragma unroll
  for (int l = 0; l < 16 / NW; ++l) {
    const int c = wid * (16 / NW) + l;  // chunk 0..15 (8 rows each)
    gload_lds16(g + (size_t)(row0 + c * 8 + rsub) * ldk + k0 + c16 * 8,
                lds + c * 512);
  }
}

// ========== QKV GEMM: m97 structure + fused epilogue (R11/R12/R16-proven) ==
// Q epilogue folds 1/sqrt(128) * log2(e) so attn uses raw exp2.
__global__ __launch_bounds__(256, 3) void gemm_qkv(const u16* __restrict__ A,
                                                   const u16* __restrict__ W,
                                                   u16* __restrict__ Oq,
                                                   u16* __restrict__ Ok,
                                                   u16* __restrict__ Ovt,
                                                   const float* __restrict__ cosb,
                                                   const float* __restrict__ sinb,
                                                   int MB, int NB, int K) {
  __shared__ __align__(16) u16 LA[128 * 64];
  __shared__ __align__(16) u16 LB[128 * 64];
  const int nwg = MB * NB;                        // %8 == 0
  const int cpx = nwg >> 3;
  const int bid = blockIdx.x;
  const int swz = (bid & 7) * cpx + (bid >> 3);   // T1: XCD chunking
  const int bm = swz % MB, bn = swz / MB;         // M-fastest 2D chunk per XCD
  const int m0 = bm * 128, n0 = bn * 128;
  const int tid = threadIdx.x, wid = tid >> 6, lane = tid & 63;
  const int wr = wid >> 1, wc = wid & 1;          // 2x2 waves, 64x64 each
  const int fr = lane & 15, fq = lane >> 4;
  f32x4 acc[4][4] = {};

  for (int k0 = 0; k0 < K; k0 += 64) {
    stage_tile<4>(A, K, m0, k0, LA, wid, lane);
    stage_tile<4>(W, K, n0, k0, LB, wid, lane);
    __syncthreads();
    s16x8 bf[4][2];
#pragma unroll
    for (int ni = 0; ni < 4; ++ni)
#pragma unroll
      for (int kk = 0; kk < 2; ++kk) {
        const int rr = wc * 64 + ni * 16 + fr;
        const int s16 = (kk * 4 + fq) ^ (rr & 7);
        bf[ni][kk] = *(const s16x8*)&LB[rr * 64 + s16 * 8];
      }
#pragma unroll
    for (int mi = 0; mi < 4; ++mi) {
      const int r = wr * 64 + mi * 16 + fr;
      const s16x8 a0 = *(const s16x8*)&LA[r * 64 + ((0 + fq) ^ (r & 7)) * 8];
      const s16x8 a1 = *(const s16x8*)&LA[r * 64 + ((4 + fq) ^ (r & 7)) * 8];
#pragma unroll
      for (int ni = 0; ni < 4; ++ni)
        acc[mi][ni] = MFMA16(a0, bf[ni][0], acc[mi][ni]);
#pragma unroll
      for (int ni = 0; ni < 4; ++ni)
        acc[mi][ni] = MFMA16(a1, bf[ni][1], acc[mi][ni]);
    }
    __syncthreads();
  }

  // epilogue: D(i,j): col = lane&15, row = (lane>>4)*4 + reg
  if (n0 < 8192) {                       // ---- Q or K: fused RoPE ----
    u16* Ob = (n0 < 4096) ? Oq : Ok;
    // Q: fold 1/sqrt(128)*log2(e) so scores arrive in exp2 domain
    const float qsc = (n0 < 4096) ? 0.12751741f : 1.0f;
    const int nc = n0 & 4095;
    const float sgn = (fr & 1) ? 1.f : -1.f;   // even lane: t0*c - t1*s
#pragma unroll
    for (int mi = 0; mi < 4; ++mi)
#pragma unroll
      for (int ni = 0; ni < 4; ++ni) {
        const int col = nc + wc * 64 + ni * 16 + fr;
        const int i0 = (col & (HD_ - 1)) >> 1;
#pragma unroll
        for (int r = 0; r < 4; ++r) {
          const int row = m0 + wr * 64 + mi * 16 + fq * 4 + r;
          const int s = row & (S_ - 1);
          const float v  = acc[mi][ni][r];
          const float vo = __shfl_xor(v, 1);
          const float c  = cosb[s * (HD_ / 2) + i0];
          const float sn = sinb[s * (HD_ / 2) + i0];
          Ob[(size_t)row * 4096 + col] = f2bf((v * c + sgn * vo * sn) * qsc);
        }
      }
  } else {                               // ---- V: write transposed (b,h,d,s)
    const int nc = n0 - 8192;
#pragma unroll
    for (int mi = 0; mi < 4; ++mi)
#pragma unroll
      for (int ni = 0; ni < 4; ++ni) {
        const int col = nc + wc * 64 + ni * 16 + fr;
        const int h = col >> 7, d = col & (HD_ - 1);
        const int row0 = m0 + wr * 64 + mi * 16 + fq * 4;
        const int bb = row0 >> 10, s0 = row0 & (S_ - 1);
        ushort4 w;
        w.x = f2bf(acc[mi][ni][0]); w.y = f2bf(acc[mi][ni][1]);
        w.z = f2bf(acc[mi][ni][2]); w.w = f2bf(acc[mi][ni][3]);
        *(ushort4*)&Ovt[((size_t)(bb * H_ + h) * HD_ + d) * S_ + s0] = w;
      }
  }
}

// ========== out-proj: m97 structure, f32 out (R17 exposed 2-phase as 600TF;
// this structure is the proven 877-950 TF one). Grid 16x32=512 blocks (2/CU).
__global__ __launch_bounds__(256, 3) void gemm_m97_out(const u16* __restrict__ A,
                                                       const u16* __restrict__ W,
                                                       float* __restrict__ Of,
                                                       int MB, int NB, int K) {
  __shared__ __align__(16) u16 LA[128 * 64];
  __shared__ __align__(16) u16 LB[128 * 64];
  const int nwg = MB * NB;                        // %8 == 0
  const int cpx = nwg >> 3;
  const int bid = blockIdx.x;
  const int swz = (bid & 7) * cpx + (bid >> 3);   // T1: XCD chunking
  const int bm = swz % MB, bn = swz / MB;         // M-fastest 2D chunk per XCD
  const int m0 = bm * 128, n0 = bn * 128;
  const int tid = threadIdx.x, wid = tid >> 6, lane = tid & 63;
  const int wr = wid >> 1, wc = wid & 1;          // 2x2 waves, 64x64 each
  const int fr = lane & 15, fq = lane >> 4;
  f32x4 acc[4][4] = {};

  for (int k0 = 0; k0 < K; k0 += 64) {
    stage_tile<4>(A, K, m0, k0, LA, wid, lane);
    stage_tile<4>(W, K, n0, k0, LB, wid, lane);
    __syncthreads();
    s16x8 bf[4][2];
#pragma unroll
    for (int ni = 0; ni < 4; ++ni)
#pragma unroll
      for (int kk = 0; kk < 2; ++kk) {
        const int rr = wc * 64 + ni * 16 + fr;
        const int s16 = (kk * 4 + fq) ^ (rr & 7);
        bf[ni][kk] = *(const s16x8*)&LB[rr * 64 + s16 * 8];
      }
#pragma unroll
    for (int mi = 0; mi < 4; ++mi) {
      const int r = wr * 64 + mi * 16 + fr;
      const s16x8 a0 = *(const s16x8*)&LA[r * 64 + ((0 + fq) ^ (r & 7)) * 8];
      const s16x8 a1 = *(const s16x8*)&LA[r * 64 + ((4 + fq) ^ (r & 7)) * 8];
#pragma unroll
      for (int ni = 0; ni < 4; ++ni)
        acc[mi][ni] = MFMA16(a0, bf[ni][0], acc[mi][ni]);
#pragma unroll
      for (int ni = 0; ni < 4; ++ni)
        acc[mi][ni] = MFMA16(a1, bf[ni][1], acc[mi][ni]);
    }
    __syncthreads();
  }

  const int Nn = NB * 128;
#pragma unroll
  for (int mi = 0; mi < 4; ++mi)
#pragma unroll
    for (int ni = 0; ni < 4; ++ni) {
      const int col = n0 + wc * 64 + ni * 16 + fr;
#pragma unroll
      for (int r = 0; r < 4; ++r) {
        const int row = m0 + wr * 64 + mi * 16 + fq * 4 + r;
        Of[(size_t)row * Nn + col] = acc[mi][ni][r];
      }
    }
}

// ---------------- Flash attention: Q-tile 128, 8 waves x 16 q-rows ---------
// Static-max softmax (R12-proven); wo f32->bf16 fused under idle HBM.
__global__ __launch_bounds__(512) void flash_attn(const u16* __restrict__ qb,
                                                  const u16* __restrict__ kb,
                                                  const u16* __restrict__ vtb,
                                                  u16* __restrict__ ab,
                                                  const float* __restrict__ wo,
                                                  u16* __restrict__ wob) {
  __shared__ __align__(16) u16 Ks[128 * 64];   // row = (kcol>>6)*64 + key
  __shared__ __align__(16) u16 Vs[128 * 64];   // row = d, cols = 64 keys
  __shared__ __align__(16) u16 Ps[8][16][72];
  const int qt = blockIdx.x, h = blockIdx.y, b = blockIdx.z;
  const int tid = threadIdx.x, wid = tid >> 6, lane = tid & 63;
  const int fr = lane & 15, fq = lane >> 4;
  const int rsub = lane >> 3;           // staging row-within-chunk
  const int c16  = (lane & 7) ^ rsub;   // pre-swizzled source col16

  {  // fused wo convert (consumer is a later dispatch; no sync needed)
    const int bidf = (b * H_ + h) * (S_ / 128) + qt;   // 0..511
    const int n8w = D_ * D_ / 8;
    for (int i = bidf * 512 + tid; i < n8w; i += 512 * 512) {
      const float4* p = (const float4*)wo + (size_t)i * 2;
      float4 a = p[0], bb4 = p[1];
      u16 us[8] = {f2bf(a.x), f2bf(a.y), f2bf(a.z), f2bf(a.w),
                   f2bf(bb4.x), f2bf(bb4.y), f2bf(bb4.z), f2bf(bb4.w)};
      *(uint4*)(wob + (size_t)i * 8) = *(uint4*)us;
    }
  }

  const int q0 = qt * 128 + wid * 16;
  s16x8 qf[4];
  {
    size_t base = (size_t)(b * S_ + q0 + fr) * D_ + h * HD_;
#pragma unroll
    for (int kk = 0; kk < 4; ++kk) qf[kk] = *(const s16x8*)&qb[base + kk * 32 + fq * 8];
  }
  f32x4 oacc[8] = {};
  float l_i[4] = {0.f, 0.f, 0.f, 0.f};     // lane-partial (16 keys/lane-group)
  const float M2 = 23.083120654f;          // static offset; cancels in normalize
  const u16* vsrc = vtb + (size_t)(b * H_ + h) * HD_ * S_;

  for (int k0 = 0; k0 < S_; k0 += 64) {
    __syncthreads();                     // prior-iter LDS reads complete
    {  // K: chunk c holds rows r=c*8+rsub, r=(kcol>>6)*64+key
      const u16* ksrc = kb + (size_t)(b * S_ + k0) * D_ + h * HD_;
#pragma unroll
      for (int l = 0; l < 2; ++l) {
        const int c = wid * 2 + l;
        const int key = (c & 7) * 8 + rsub, half = c >> 3;
        gload_lds16(ksrc + (size_t)key * D_ + half * 64 + c16 * 8, Ks + c * 512);
      }
      stage_tile<8>(vsrc, S_, 0, k0, Vs, wid, lane);
    }
    __syncthreads();                     // drains vmcnt: tiles resident
    f32x4 sacc[4] = {};
    __builtin_amdgcn_s_setprio(1);
#pragma unroll
    for (int kk = 0; kk < 4; ++kk)
#pragma unroll
      for (int nb = 0; nb < 4; ++nb)
        sacc[nb] = MFMA16(qf[kk],
            *(const s16x8*)&Ks[((kk >> 1) * 64 + nb * 16 + fr) * 64 +
                               ((((kk & 1) * 4 + fq) ^ (fr & 7)) * 8)],
            sacc[nb]);
    __builtin_amdgcn_s_setprio(0);
    // static-max softmax: 16 exp2 + 4 adds + LDS writes, no cross-lane ops
#pragma unroll
    for (int r = 0; r < 4; ++r) {
      const float p0 = __builtin_amdgcn_exp2f(sacc[0][r] - M2);
      const float p1 = __builtin_amdgcn_exp2f(sacc[1][r] - M2);
      const float p2 = __builtin_amdgcn_exp2f(sacc[2][r] - M2);
      const float p3 = __builtin_amdgcn_exp2f(sacc[3][r] - M2);
      l_i[r] += (p0 + p1) + (p2 + p3);
      Ps[wid][fq * 4 + r][0 * 16 + fr] = f2bf(p0);
      Ps[wid][fq * 4 + r][1 * 16 + fr] = f2bf(p1);
      Ps[wid][fq * 4 + r][2 * 16 + fr] = f2bf(p2);
      Ps[wid][fq * 4 + r][3 * 16 + fr] = f2bf(p3);
    }
    s16x8 pf0 = *(const s16x8*)&Ps[wid][fr][fq * 8];
    s16x8 pf1 = *(const s16x8*)&Ps[wid][fr][32 + fq * 8];
    __builtin_amdgcn_s_setprio(1);
#pragma unroll
    for (int db = 0; db < 8; ++db)
      oacc[db] = MFMA16(pf0,
          *(const s16x8*)&Vs[(db * 16 + fr) * 64 + ((fq ^ (fr & 7)) * 8)], oacc[db]);
#pragma unroll
    for (int db = 0; db < 8; ++db)
      oacc[db] = MFMA16(pf1,
          *(const s16x8*)&Vs[(db * 16 + fr) * 64 + (((4 + fq) ^ (fr & 7)) * 8)], oacc[db]);
    __builtin_amdgcn_s_setprio(0);
  }
  // epilogue: reduce lane-partial l across the 16 fr lanes, normalize, store
#pragma unroll
  for (int r = 0; r < 4; ++r) {
    float sum = l_i[r];
#pragma unroll
    for (int o = 1; o < 16; o <<= 1) sum += __shfl_xor(sum, o);
    const float inv = 1.0f / sum;
    size_t rowbase = (size_t)(b * S_ + q0 + fq * 4 + r) * D_ + h * HD_;
#pragma unroll
    for (int db = 0; db < 8; ++db)
      ab[rowbase + db * 16 + fr] = f2bf(oacc[db][r] * inv);
  }
}

// ---------------------------------------------------------------------------
extern "C" void kernel_launch(void* const* d_in, const int* in_sizes, int n_in,
                              void* d_out, int out_size, void* d_ws, size_t ws_size,
                              hipStream_t stream) {
  const float* x    = (const float*)d_in[0];
  const float* wq   = (const float*)d_in[1];
  const float* wk   = (const float*)d_in[2];
  const float* wv   = (const float*)d_in[3];
  const float* wo   = (const float*)d_in[4];
  const float* fcos = (const float*)d_in[7];
  const float* fsin = (const float*)d_in[8];
  float* out = (float*)d_out;

  u16* xb  = (u16*)d_ws;                      // T*D
  u16* wqb = xb + (size_t)T_ * D_;            // D*D each; wq|wk|wv CONTIGUOUS
  u16* wob = wqb + 3 * (size_t)D_ * D_;
  u16* qb  = wob + (size_t)D_ * D_;           // T*D each
  u16* kb  = qb + (size_t)T_ * D_;
  u16* vtb = kb + (size_t)T_ * D_;
  u16* ab  = vtb + (size_t)T_ * D_;

  // convert x + wq/wk/wv (wo converted inside flash_attn under idle HBM)
  cvt_all<<<2048, 256, 0, stream>>>(x, wq, wk, wv, xb, wqb);

  // fused QKV + RoPE(+exp2-domain scale) + V-transpose (R16: 217us proven)
  gemm_qkv<<<1536, 256, 0, stream>>>(xb, wqb, qb, kb, vtb, fcos, fsin, 16, 96, D_);

  flash_attn<<<dim3(S_ / 128, H_, B_), 512, 0, stream>>>(qb, kb, vtb, ab, wo, wob);

  // output projection: m97 structure, 16x32 = 512 blocks (2/CU)
  gemm_m97_out<<<512, 256, 0, stream>>>(ab, wob, out, 16, 32, D_);
}